// Round 3
// baseline (428.761 us; speedup 1.0000x reference)
//
#include <hip/hip_runtime.h>
#include <math.h>

#define SLOPE 0.2f

__device__ __forceinline__ float lrelu(float x) { return x > 0.f ? x : SLOPE * x; }

// bf16 helpers
__device__ __forceinline__ float bflo(unsigned int u) { return __uint_as_float(u << 16); }
__device__ __forceinline__ float bfhi(unsigned int u) { return __uint_as_float(u & 0xffff0000u); }
__device__ __forceinline__ unsigned short f2bf(float f) {   // round-nearest-even
    unsigned int u = __float_as_uint(f);
    unsigned int r = u + 0x7fffu + ((u >> 16) & 1u);
    return (unsigned short)(r >> 16);
}

typedef short frag8 __attribute__((ext_vector_type(8)));   // 8 bf16 (4 VGPR)
typedef float f32x4 __attribute__((ext_vector_type(4)));   // MFMA acc

// ---------------------------------------------------------------------------
// One-off: Wt[n][k] = bf16(W[k][n]) for W1 and W2 (128x128 each). Also zeroes
// bcnt.
// ---------------------------------------------------------------------------
__global__ __launch_bounds__(256) void wtrans_kernel(
    const float* __restrict__ W1, const float* __restrict__ W2,
    unsigned short* __restrict__ Wt1, unsigned short* __restrict__ Wt2,
    int* __restrict__ bcnt, int nbcnt)
{
    int idx = blockIdx.x * 256 + threadIdx.x;   // grid 128 -> 32768
    if (idx < nbcnt) bcnt[idx] = 0;
    const float* W = W1;
    unsigned short* Wt = Wt1;
    int i = idx;
    if (idx >= 16384) { W = W2; Wt = Wt2; i = idx - 16384; }
    int n = i >> 7, k = i & 127;
    Wt[i] = f2bf(W[k * 128 + n]);
}

// ---------------------------------------------------------------------------
// MFMA transform body (CIN=128 -> COUT=128, H=4). Used standalone for layer 1
// (fused with bin), and as the T-phase of the agg1+T2 fused kernel.
// Block: 64 nodes x 128 cols, 4 waves; wave w = head w, 8 acc tiles.
// ---------------------------------------------------------------------------
#define TF_MB 64
#define TF_LDK 136

// Compute section only: assumes xs (64 rows x 128 bf16, stride TF_LDK) and wt
// (128 rows x 128 bf16, stride TF_LDK) are staged and synced.
__device__ __forceinline__ void transform_compute(
    int node0, const float* __restrict__ a_src, const float* __restrict__ a_dst,
    unsigned short* __restrict__ hout, float* __restrict__ alsrc,
    float* __restrict__ aldst, int N,
    unsigned short* xs, const unsigned short* wt)
{
    constexpr int LDK = TF_LDK;
    const int t = threadIdx.x;
    const int w    = t >> 6;             // wave = head
    const int lane = t & 63;
    const int r    = lane & 15;
    const int q    = lane >> 4;

    f32x4 acc[4][2];
#pragma unroll
    for (int mt = 0; mt < 4; ++mt)
#pragma unroll
        for (int nl = 0; nl < 2; ++nl)
            acc[mt][nl] = (f32x4){0.f, 0.f, 0.f, 0.f};

#pragma unroll
    for (int kk = 0; kk < 4; ++kk) {
        const int kof = kk * 32 + q * 8;
        frag8 b0 = *(const frag8*)&wt[(w * 32 + r) * LDK + kof];
        frag8 b1 = *(const frag8*)&wt[(w * 32 + 16 + r) * LDK + kof];
#pragma unroll
        for (int mt = 0; mt < 4; ++mt) {
            frag8 a = *(const frag8*)&xs[(mt * 16 + r) * LDK + kof];
            acc[mt][0] = __builtin_amdgcn_mfma_f32_16x16x32_bf16(a, b0, acc[mt][0], 0, 0, 0);
            acc[mt][1] = __builtin_amdgcn_mfma_f32_16x16x32_bf16(a, b1, acc[mt][1], 0, 0, 0);
        }
    }

    // ---- logits from fp32 acc ----
    const float as0 = a_src[w * 32 + r],      ad0 = a_dst[w * 32 + r];
    const float as1 = a_src[w * 32 + 16 + r], ad1 = a_dst[w * 32 + 16 + r];
#pragma unroll
    for (int mt = 0; mt < 4; ++mt) {
#pragma unroll
        for (int reg = 0; reg < 4; ++reg) {
            float s = acc[mt][0][reg] * as0 + acc[mt][1][reg] * as1;
            float d = acc[mt][0][reg] * ad0 + acc[mt][1][reg] * ad1;
#pragma unroll
            for (int off = 1; off < 16; off <<= 1) {
                s += __shfl_xor(s, off);
                d += __shfl_xor(d, off);
            }
            if (r == 0) {
                int m = mt * 16 + q * 4 + reg;
                int n = node0 + m;
                if (n < N) {
                    alsrc[n * 4 + w] = s;
                    aldst[n * 4 + w] = d;
                }
            }
        }
    }

    // ---- h -> LDS (bf16, D-layout scatter), then coalesced global store ----
    __syncthreads();
#pragma unroll
    for (int mt = 0; mt < 4; ++mt)
#pragma unroll
        for (int nl = 0; nl < 2; ++nl)
#pragma unroll
            for (int reg = 0; reg < 4; ++reg) {
                int m = mt * 16 + q * 4 + reg;
                int n = w * 32 + nl * 16 + r;
                xs[m * LDK + n] = f2bf(acc[mt][nl][reg]);
            }
    __syncthreads();
    {
        int row = t >> 2, cbase = (t & 3) * 32;      // 4 threads/row, 32 bf16 each
        if (node0 + row < N) {
            uint4* dst = (uint4*)(hout + (size_t)(node0 + row) * 128 + cbase);
#pragma unroll
            for (int j = 0; j < 4; ++j)
                dst[j] = *(const uint4*)&xs[row * LDK + cbase + j * 8];
        }
    }
}

// Full transform (stages x from global, fp32 input) — layer 1.
__device__ __forceinline__ void transform_body_f32(
    int bid, const float* __restrict__ xf, const unsigned short* __restrict__ Wt,
    const float* __restrict__ a_src, const float* __restrict__ a_dst,
    unsigned short* __restrict__ hout, float* __restrict__ alsrc,
    float* __restrict__ aldst, int N,
    unsigned short* xs, unsigned short* wt)
{
    constexpr int LDK = TF_LDK;
    const int node0 = bid * TF_MB;
    const int t = threadIdx.x;

    for (int i = t; i < TF_MB * 32; i += 256) {
        int row = i >> 5, col4 = i & 31;
        ushort4 o;
        if (node0 + row < N) {
            float4 v = ((const float4*)(xf + (size_t)(node0 + row) * 128))[col4];
            o.x = f2bf(v.x); o.y = f2bf(v.y); o.z = f2bf(v.z); o.w = f2bf(v.w);
        } else {
            o.x = o.y = o.z = o.w = 0;
        }
        *(ushort4*)&xs[row * LDK + col4 * 4] = o;
    }
    for (int i = t; i < 2048; i += 256) {                // Wt: 2048 x 16B
        int n = i >> 4, k16 = i & 15;
        uint4 v = ((const uint4*)Wt)[i];
        *(uint4*)&wt[n * LDK + k16 * 8] = v;
    }
    __syncthreads();
    transform_compute(node0, a_src, a_dst, hout, alsrc, aldst, N, xs, wt);
}

// ---------------------------------------------------------------------------
// CSR build, bucket-local counting sort (64 dst nodes per bucket).
// ---------------------------------------------------------------------------
#define BKT_CAP 2048
#define NBKT_MAX 1024
#define CH_BIN 4096

__device__ __forceinline__ void bin_body(
    int bid, const int* __restrict__ src, const int* __restrict__ dst,
    int* __restrict__ bcnt, unsigned int* __restrict__ tmp, int E, int nbkt,
    int* hist, int* base)
{
    const int e0 = bid * CH_BIN;
    const int e1 = min(e0 + CH_BIN, E);

    for (int b = threadIdx.x; b < nbkt; b += 256) hist[b] = 0;
    __syncthreads();
    for (int e = e0 + threadIdx.x; e < e1; e += 256) {
        int d = __builtin_nontemporal_load(dst + e);
        atomicAdd(&hist[d >> 6], 1);
    }
    __syncthreads();
    for (int b = threadIdx.x; b < nbkt; b += 256) {
        int c = hist[b];
        base[b] = (c > 0) ? atomicAdd(&bcnt[b << 4], c) : 0;  // 64B-strided
        hist[b] = 0;
    }
    __syncthreads();
    for (int e = e0 + threadIdx.x; e < e1; e += 256) {
        int d = __builtin_nontemporal_load(dst + e);
        int s = __builtin_nontemporal_load(src + e);
        int b = d >> 6;
        int pos = base[b] + atomicAdd(&hist[b], 1);
        if (pos < BKT_CAP)
            tmp[((size_t)b << 11) + pos] =
                ((unsigned int)s << 6) | (unsigned int)(d & 63);
    }
}

// Fused: blocks [0, nbin) bin edges, blocks [nbin, ...) run the layer-1 MFMA
// transform (independent work, shared dispatch).
__global__ __launch_bounds__(256) void bin_transform_kernel(
    const int* __restrict__ src, const int* __restrict__ dst,
    int* __restrict__ bcnt, unsigned int* __restrict__ tmp, int E, int nbkt,
    const float* __restrict__ xin, const unsigned short* __restrict__ Wt,
    const float* __restrict__ a_src, const float* __restrict__ a_dst,
    unsigned short* __restrict__ hout, float* __restrict__ alsrc,
    float* __restrict__ aldst, int N, int nbin)
{
    __shared__ __align__(16) unsigned short smem[TF_MB * TF_LDK + 128 * TF_LDK];
    if ((int)blockIdx.x < nbin) {
        int* hist = (int*)smem;
        bin_body(blockIdx.x, src, dst, bcnt, tmp, E, nbkt, hist, hist + NBKT_MAX);
    } else {
        transform_body_f32(blockIdx.x - nbin, xin, Wt, a_src, a_dst,
                           hout, alsrc, aldst, N, smem, smem + TF_MB * TF_LDK);
    }
}

__global__ __launch_bounds__(256) void bucket_csr_kernel(
    const unsigned int* __restrict__ tmp, const int* __restrict__ bcnt,
    int* __restrict__ deg, int* __restrict__ offsets,
    int* __restrict__ src_sorted, int N)
{
    int b = blockIdx.x;
    __shared__ int hist[64];
    if (threadIdx.x < 64) hist[threadIdx.x] = 0;
    __syncthreads();
    int cnt = min(bcnt[b << 4], BKT_CAP);
    const unsigned int* tb = tmp + ((size_t)b << 11);
    for (int i = threadIdx.x; i < cnt; i += 256)
        atomicAdd(&hist[tb[i] & 63u], 1);
    __syncthreads();
    if (threadIdx.x < 64) {                          // wave 0: 64-wide scan
        int v = hist[threadIdx.x];
        int incl = v;
#pragma unroll
        for (int off = 1; off < 64; off <<= 1) {
            int t2 = __shfl_up(incl, off);
            if ((int)threadIdx.x >= off) incl += t2;
        }
        int excl = incl - v;
        int node = (b << 6) + threadIdx.x;
        if (node < N) {
            deg[node] = v;
            offsets[node] = (b << 11) + excl;
        }
        hist[threadIdx.x] = excl;                    // reuse as cursor
    }
    __syncthreads();
    for (int i = threadIdx.x; i < cnt; i += 256) {
        unsigned int p = tb[i];
        int pos = atomicAdd(&hist[p & 63u], 1);
        src_sorted[((size_t)b << 11) + pos] = (int)(p >> 6);
    }
}

// ---------------------------------------------------------------------------
// 16-node H=4 aggregation batch body (256 threads = 16 nodes x 16 threads,
// 8 channels/thread). Produces o[8] (bias + optional ELU applied) in regs.
// Shared scratch: s_src[16][32] int, s_w 4 head-planes, s_nch[16].
// ---------------------------------------------------------------------------
#define AG_CHUNK 32
#define AG_STRIDE (AG_CHUNK + 4)            // 36 floats
#define AG_PLANE  (16 * AG_STRIDE + 8)      // 584 floats per head plane
#define AG_SCRATCH_INTS (16 * AG_CHUNK + 4 * AG_PLANE + 16)   // 2864 ints

__device__ __forceinline__ void fma8(const uint4& p, float w, float* a) {
    a[0] += w * bflo(p.x); a[1] += w * bfhi(p.x);
    a[2] += w * bflo(p.y); a[3] += w * bfhi(p.y);
    a[4] += w * bflo(p.z); a[5] += w * bfhi(p.z);
    a[6] += w * bflo(p.w); a[7] += w * bfhi(p.w);
}

template <bool DO_ELU>
__device__ __forceinline__ void agg16_node(
    int n, bool valid, int g, int lt,
    const int* __restrict__ offsets, const int* __restrict__ deg_arr,
    const int* __restrict__ src_sorted, const uint4* __restrict__ h4,
    const float* __restrict__ alsrc, const float* __restrict__ aldst,
    const float* __restrict__ bias, int* scratch, float* o)
{
    int*   s_src = scratch;                         // [16][AG_CHUNK]
    float* s_w   = (float*)(scratch + 16 * AG_CHUNK);
    int*   s_nch = scratch + 16 * AG_CHUNK + 4 * AG_PLANE;

    int off0 = 0, deg = 0;
    if (valid) { off0 = offsets[n]; deg = deg_arr[n]; }
    if (lt == 0) s_nch[g] = (deg + AG_CHUNK - 1) / AG_CHUNK;
    __syncthreads();
    int maxch = 0;
#pragma unroll
    for (int i = 0; i < 16; ++i) maxch = max(maxch, s_nch[i]);

    const int hh = lt >> 2;                         // head = (lt*8)/32
    float adv[4] = {0.f, 0.f, 0.f, 0.f};
    if (valid) {
        float4 t4 = ((const float4*)aldst)[n];
        adv[0] = t4.x; adv[1] = t4.y; adv[2] = t4.z; adv[3] = t4.w;
    }

    // prefetch self-loop inputs
    uint4 pself = make_uint4(0u, 0u, 0u, 0u);
    float als_self = 0.f;
    if (valid) {
        pself = h4[(size_t)n * 16 + lt];
        als_self = alsrc[n * 4 + hh];
    }

    const int wbase = hh * AG_PLANE + g * AG_STRIDE;

    float a[8] = {0.f, 0.f, 0.f, 0.f, 0.f, 0.f, 0.f, 0.f};
    float den = 0.f;
    for (int ch = 0; ch < maxch; ++ch) {
        int base = ch * AG_CHUNK;
        int cnt = deg - base;
        cnt = cnt < 0 ? 0 : (cnt > AG_CHUNK ? AG_CHUNK : cnt);
        __syncthreads();
        for (int i = lt; i < cnt; i += 16) {
            int s = __builtin_nontemporal_load(src_sorted + off0 + base + i);
            s_src[g * AG_CHUNK + i] = s;
            float4 av = ((const float4*)alsrc)[s];
            s_w[0 * AG_PLANE + g * AG_STRIDE + i] = __expf(lrelu(av.x + adv[0]));
            s_w[1 * AG_PLANE + g * AG_STRIDE + i] = __expf(lrelu(av.y + adv[1]));
            s_w[2 * AG_PLANE + g * AG_STRIDE + i] = __expf(lrelu(av.z + adv[2]));
            s_w[3 * AG_PLANE + g * AG_STRIDE + i] = __expf(lrelu(av.w + adv[3]));
        }
        __syncthreads();
        int i = 0;
        for (; i + 3 < cnt; i += 4) {
            int s0 = s_src[g * AG_CHUNK + i],     s1 = s_src[g * AG_CHUNK + i + 1];
            int s2 = s_src[g * AG_CHUNK + i + 2], s3 = s_src[g * AG_CHUNK + i + 3];
            float4 wv = *(const float4*)&s_w[wbase + i];
            uint4 p0 = h4[(size_t)s0 * 16 + lt];
            uint4 p1 = h4[(size_t)s1 * 16 + lt];
            uint4 p2 = h4[(size_t)s2 * 16 + lt];
            uint4 p3 = h4[(size_t)s3 * 16 + lt];
            fma8(p0, wv.x, a);
            fma8(p1, wv.y, a);
            fma8(p2, wv.z, a);
            fma8(p3, wv.w, a);
            den += (wv.x + wv.y) + (wv.z + wv.w);
        }
        for (; i < cnt; ++i) {
            int s0 = s_src[g * AG_CHUNK + i];
            float w0 = s_w[wbase + i];
            uint4 p0 = h4[(size_t)s0 * 16 + lt];
            fma8(p0, w0, a);
            den += w0;
        }
    }

    float wself = __expf(lrelu(als_self + adv[hh]));
    fma8(pself, wself, a);
    den += wself + 1e-16f;
    float inv = 1.f / den;
    float4 bv0 = ((const float4*)bias)[lt * 2];
    float4 bv1 = ((const float4*)bias)[lt * 2 + 1];
    o[0] = a[0] * inv + bv0.x; o[1] = a[1] * inv + bv0.y;
    o[2] = a[2] * inv + bv0.z; o[3] = a[3] * inv + bv0.w;
    o[4] = a[4] * inv + bv1.x; o[5] = a[5] * inv + bv1.y;
    o[6] = a[6] * inv + bv1.z; o[7] = a[7] * inv + bv1.w;
    if (DO_ELU) {
#pragma unroll
        for (int q = 0; q < 8; ++q)
            o[q] = o[q] > 0.f ? o[q] : __expf(o[q]) - 1.f;
    }
}

// ---------------------------------------------------------------------------
// FUSED agg(layer L, H=4) + MFMA transform (layer L+1): block owns 64 nodes.
// Aggregates them (4 batches of 16), deposits ELU'd bf16 rows directly into
// the transform's LDS x-tile (no fb16 global roundtrip), then runs the
// 128->128 MFMA transform producing h_next + logits_next.
// LDS: xs (17.4 KB) + wt (34.8 KB, aliased as agg scratch before staging).
// ---------------------------------------------------------------------------
__global__ __launch_bounds__(256) void aggtrans_mfma_kernel(
    const int* __restrict__ offsets, const int* __restrict__ deg_arr,
    const int* __restrict__ src_sorted,
    const unsigned short* __restrict__ h, const float* __restrict__ alsrc,
    const float* __restrict__ aldst, const float* __restrict__ bias,
    const unsigned short* __restrict__ Wt,
    const float* __restrict__ a_src, const float* __restrict__ a_dst,
    unsigned short* __restrict__ hout, float* __restrict__ alsrc_o,
    float* __restrict__ aldst_o, int N)
{
    __shared__ __align__(16) unsigned short xs[TF_MB * TF_LDK];
    __shared__ __align__(16) unsigned short wt[128 * TF_LDK];
    int* scratch = (int*)wt;                         // aliased pre-staging

    const int node0 = blockIdx.x * 64;
    const int g  = threadIdx.x >> 4;
    const int lt = threadIdx.x & 15;
    const uint4* h4 = (const uint4*)h;

    for (int b = 0; b < 4; ++b) {
        int row = b * 16 + g;
        int n = node0 + row;
        float o[8];
        agg16_node<true>(n, n < N, g, lt, offsets, deg_arr, src_sorted,
                         h4, alsrc, aldst, bias, scratch, o);
        uint4 pk;
        pk.x = (unsigned int)f2bf(o[0]) | ((unsigned int)f2bf(o[1]) << 16);
        pk.y = (unsigned int)f2bf(o[2]) | ((unsigned int)f2bf(o[3]) << 16);
        pk.z = (unsigned int)f2bf(o[4]) | ((unsigned int)f2bf(o[5]) << 16);
        pk.w = (unsigned int)f2bf(o[6]) | ((unsigned int)f2bf(o[7]) << 16);
        *(uint4*)&xs[row * TF_LDK + lt * 8] = pk;
    }
    __syncthreads();                                  // agg done; scratch free
    for (int i = threadIdx.x; i < 2048; i += 256) {   // stage Wt (overwrites scratch)
        int nn = i >> 4, k16 = i & 15;
        uint4 v = ((const uint4*)Wt)[i];
        *(uint4*)&wt[nn * TF_LDK + k16 * 8] = v;
    }
    __syncthreads();
    transform_compute(node0, a_src, a_dst, hout, alsrc_o, aldst_o, N, xs, wt);
}

// ---------------------------------------------------------------------------
// FUSED agg(layer 2, H=4) + VALU transform (layer 3, 128->32, H=1).
// Aggregated rows kept fp32 in LDS (more accurate than the old bf16 hop).
// ---------------------------------------------------------------------------
__global__ __launch_bounds__(256) void aggtrans_valu_kernel(
    const int* __restrict__ offsets, const int* __restrict__ deg_arr,
    const int* __restrict__ src_sorted,
    const unsigned short* __restrict__ h, const float* __restrict__ alsrc,
    const float* __restrict__ aldst, const float* __restrict__ bias,
    const float* __restrict__ W,
    const float* __restrict__ a_src, const float* __restrict__ a_dst,
    unsigned short* __restrict__ hout, float* __restrict__ alsrc_o,
    float* __restrict__ aldst_o, int N)
{
    constexpr int LDKF = 132;
    __shared__ __align__(16) float xs[64 * LDKF];     // 33.8 KB
    __shared__ int scratch[AG_SCRATCH_INTS];          // 11.5 KB (separate)

    const int node0 = blockIdx.x * 64;
    const int g  = threadIdx.x >> 4;
    const int lt = threadIdx.x & 15;
    const uint4* h4 = (const uint4*)h;

    for (int b = 0; b < 4; ++b) {
        int row = b * 16 + g;
        int n = node0 + row;
        float o[8];
        agg16_node<true>(n, n < N, g, lt, offsets, deg_arr, src_sorted,
                         h4, alsrc, aldst, bias, scratch, o);
        float* xp = &xs[row * LDKF + lt * 8];
        ((float4*)xp)[0] = make_float4(o[0], o[1], o[2], o[3]);
        ((float4*)xp)[1] = make_float4(o[4], o[5], o[6], o[7]);
    }
    __syncthreads();

    // ---- layer-3 transform: 64 nodes, JT=8 cols-of-4, NPT=2 rows/thread ----
    const int jt = threadIdx.x & 7;
    const int g2 = threadIdx.x >> 3;

    float4 acc[2];
    acc[0] = make_float4(0.f, 0.f, 0.f, 0.f);
    acc[1] = make_float4(0.f, 0.f, 0.f, 0.f);

    const float4* Wf4 = (const float4*)W;
    for (int k4 = 0; k4 < 32; ++k4) {
        float4 w0 = Wf4[(4 * k4 + 0) * 8 + jt];
        float4 w1 = Wf4[(4 * k4 + 1) * 8 + jt];
        float4 w2 = Wf4[(4 * k4 + 2) * 8 + jt];
        float4 w3 = Wf4[(4 * k4 + 3) * 8 + jt];
#pragma unroll
        for (int m = 0; m < 2; ++m) {
            float4 xv = *(const float4*)&xs[(g2 * 2 + m) * LDKF + (k4 << 2)];
            acc[m].x += xv.x * w0.x + xv.y * w1.x + xv.z * w2.x + xv.w * w3.x;
            acc[m].y += xv.x * w0.y + xv.y * w1.y + xv.z * w2.y + xv.w * w3.y;
            acc[m].z += xv.x * w0.z + xv.y * w1.z + xv.z * w2.z + xv.w * w3.z;
            acc[m].w += xv.x * w0.w + xv.y * w1.w + xv.z * w2.w + xv.w * w3.w;
        }
    }

    const float4 as4 = ((const float4*)a_src)[jt];
    const float4 ad4 = ((const float4*)a_dst)[jt];

#pragma unroll
    for (int m = 0; m < 2; ++m) {
        int n = node0 + g2 * 2 + m;
        float4 v = acc[m];
        float sv = v.x * as4.x + v.y * as4.y + v.z * as4.z + v.w * as4.w;
        float dv = v.x * ad4.x + v.y * ad4.y + v.z * ad4.z + v.w * ad4.w;
#pragma unroll
        for (int off = 4; off >= 1; off >>= 1) {
            sv += __shfl_xor(sv, off);
            dv += __shfl_xor(dv, off);
        }
        if (n < N) {
            ushort4 hp;
            hp.x = f2bf(v.x); hp.y = f2bf(v.y);
            hp.z = f2bf(v.z); hp.w = f2bf(v.w);
            ((ushort4*)(hout + (size_t)n * 32))[jt] = hp;
            if (jt == 0) {
                alsrc_o[n] = sv;
                aldst_o[n] = dv;
            }
        }
    }
}

// ---------------------------------------------------------------------------
// Layer-3 aggregation (H=1, C=32) with fused classification head.
// ---------------------------------------------------------------------------
__global__ __launch_bounds__(256) void gat_agg3_kernel(
    const int* __restrict__ offsets, const int* __restrict__ deg_arr,
    const int* __restrict__ src_sorted,
    const unsigned short* __restrict__ h, const float* __restrict__ alsrc,
    const float* __restrict__ aldst, const float* __restrict__ bias,
    float* __restrict__ link_out, const float* __restrict__ Wc,
    const float* __restrict__ bc, float* __restrict__ node_out, int N)
{
    constexpr int TPN = 4;
    constexpr int NPB = 64;
    constexpr int CHUNK = 32;
    constexpr int CH_STRIDE = CHUNK + 4;
    __shared__ int   s_src[NPB][CHUNK];
    __shared__ float s_w[NPB * CH_STRIDE + 8];
    __shared__ int   s_nch[NPB];

    const int g  = threadIdx.x / TPN;
    const int lt = threadIdx.x % TPN;
    const int n  = blockIdx.x * NPB + g;
    const bool valid = n < N;

    int off0 = 0, deg = 0;
    if (valid) { off0 = offsets[n]; deg = deg_arr[n]; }
    if (lt == 0) s_nch[g] = (deg + CHUNK - 1) / CHUNK;
    __syncthreads();
    int maxch = 0;
    for (int i = threadIdx.x & 63; i < NPB; i += 64)
        maxch = max(maxch, s_nch[i]);
#pragma unroll
    for (int off = 32; off >= 1; off >>= 1)
        maxch = max(maxch, __shfl_xor(maxch, off));

    float adv0 = valid ? aldst[n] : 0.f;

    const uint4* h4 = (const uint4*)h;
    uint4 pself = make_uint4(0u, 0u, 0u, 0u);
    float als_self = 0.f;
    if (valid) {
        pself = h4[(size_t)n * TPN + lt];
        als_self = alsrc[n];
    }

    const int wbase = g * CH_STRIDE;

    float a[8] = {0.f, 0.f, 0.f, 0.f, 0.f, 0.f, 0.f, 0.f};
    float den = 0.f;
    for (int ch = 0; ch < maxch; ++ch) {
        int base = ch * CHUNK;
        int cnt = deg - base;
        cnt = cnt < 0 ? 0 : (cnt > CHUNK ? CHUNK : cnt);
        __syncthreads();
        for (int i = lt; i < cnt; i += TPN) {
            int s = __builtin_nontemporal_load(src_sorted + off0 + base + i);
            s_src[g][i] = s;
            s_w[wbase + i] = __expf(lrelu(alsrc[s] + adv0));
        }
        __syncthreads();
        int i = 0;
        for (; i + 3 < cnt; i += 4) {
            int s0 = s_src[g][i],     s1 = s_src[g][i + 1];
            int s2 = s_src[g][i + 2], s3 = s_src[g][i + 3];
            float4 wv = *(const float4*)&s_w[wbase + i];
            uint4 p0 = h4[(size_t)s0 * TPN + lt];
            uint4 p1 = h4[(size_t)s1 * TPN + lt];
            uint4 p2 = h4[(size_t)s2 * TPN + lt];
            uint4 p3 = h4[(size_t)s3 * TPN + lt];
            fma8(p0, wv.x, a);
            fma8(p1, wv.y, a);
            fma8(p2, wv.z, a);
            fma8(p3, wv.w, a);
            den += (wv.x + wv.y) + (wv.z + wv.w);
        }
        for (; i < cnt; ++i) {
            int s0 = s_src[g][i];
            float w0 = s_w[wbase + i];
            uint4 p0 = h4[(size_t)s0 * TPN + lt];
            fma8(p0, w0, a);
            den += w0;
        }
    }

    if (valid) {
        float wself = __expf(lrelu(als_self + adv0));
        fma8(pself, wself, a);
        den += wself + 1e-16f;
        float inv = 1.f / den;
        float4 bv0 = ((const float4*)bias)[lt * 2];
        float4 bv1 = ((const float4*)bias)[lt * 2 + 1];
        float o[8];
        o[0] = a[0] * inv + bv0.x; o[1] = a[1] * inv + bv0.y;
        o[2] = a[2] * inv + bv0.z; o[3] = a[3] * inv + bv0.w;
        o[4] = a[4] * inv + bv1.x; o[5] = a[5] * inv + bv1.y;
        o[6] = a[6] * inv + bv1.z; o[7] = a[7] * inv + bv1.w;
        float4* op = (float4*)(link_out + (size_t)n * 32);
        op[lt * 2]     = make_float4(o[0], o[1], o[2], o[3]);
        op[lt * 2 + 1] = make_float4(o[4], o[5], o[6], o[7]);
        // fused head
        float s0 = 0.f, s1 = 0.f;
#pragma unroll
        for (int q = 0; q < 8; ++q) {
            int c = lt * 8 + q;
            s0 += o[q] * Wc[c * 2];
            s1 += o[q] * Wc[c * 2 + 1];
        }
        s0 += __shfl_xor(s0, 1); s0 += __shfl_xor(s0, 2);
        s1 += __shfl_xor(s1, 1); s1 += __shfl_xor(s1, 2);
        if (lt == 0) {
            node_out[(size_t)n * 2]     = s0 + bc[0];
            node_out[(size_t)n * 2 + 1] = s1 + bc[1];
        }
    }
}

extern "C" void kernel_launch(void* const* d_in, const int* in_sizes, int n_in,
                              void* d_out, int out_size, void* d_ws, size_t ws_size,
                              hipStream_t stream)
{
    const float* x   = (const float*)d_in[0];
    const int*   ei  = (const int*)d_in[1];
    const float* W1  = (const float*)d_in[2];
    const float* a1s = (const float*)d_in[3];
    const float* a1d = (const float*)d_in[4];
    const float* b1  = (const float*)d_in[5];
    const float* W2  = (const float*)d_in[6];
    const float* a2s = (const float*)d_in[7];
    const float* a2d = (const float*)d_in[8];
    const float* b2  = (const float*)d_in[9];
    const float* W3  = (const float*)d_in[10];
    const float* a3s = (const float*)d_in[11];
    const float* a3d = (const float*)d_in[12];
    const float* b3  = (const float*)d_in[13];
    const float* Wc  = (const float*)d_in[14];
    const float* bc  = (const float*)d_in[15];

    const int N = in_sizes[0] / 128;
    const int E = in_sizes[1] / 2;
    const int* srcIdx = ei;
    const int* dstIdx = ei + E;

    const int NBKT = (N + 63) >> 6;

    // ws layout
    float* alsrc1 = (float*)d_ws;                         // N*4
    float* aldst1 = alsrc1 + (size_t)N * 4;               // N*4
    float* alsrc2 = aldst1 + (size_t)N * 4;               // N*4
    float* aldst2 = alsrc2 + (size_t)N * 4;               // N*4
    float* alsrc3 = aldst2 + (size_t)N * 4;               // N
    float* aldst3 = alsrc3 + (size_t)N;                   // N
    unsigned short* h1 = (unsigned short*)(aldst3 + (size_t)N);  // N*128 bf16
    unsigned short* h2 = h1 + (size_t)N * 128;            // N*128 bf16
    unsigned short* h3 = h2 + (size_t)N * 128;            // N*32 bf16
    int* deg        = (int*)(h3 + (size_t)N * 32);        // N
    int* offsets    = deg + N;                            // N
    uintptr_t wp = ((uintptr_t)(offsets + N) + 15) & ~(uintptr_t)15;
    unsigned short* wt1 = (unsigned short*)wp;            // 16384 bf16
    unsigned short* wt2 = wt1 + 16384;                    // 16384 bf16
    int* bcnt       = (int*)(wt2 + 16384);                // NBKT*16 (64B-strided)
    int* src_sorted = bcnt + (size_t)NBKT * 16;           // NBKT*BKT_CAP
    unsigned int* tmp = (unsigned int*)(src_sorted + (size_t)NBKT * BKT_CAP);

    float* node_out = (float*)d_out;                      // N*2
    float* link_out = node_out + (size_t)N * 2;           // N*32

    const int nbBin = (E + CH_BIN - 1) / CH_BIN;
    const int nbT   = (N + 63) / 64;

    // 1. W pre-transpose (bf16) + bcnt zero
    wtrans_kernel<<<128, 256, 0, stream>>>(W1, W2, wt1, wt2, bcnt, NBKT * 16);

    // 2. edge binning ∥ layer-1 MFMA transform
    bin_transform_kernel<<<nbBin + nbT, 256, 0, stream>>>(
        srcIdx, dstIdx, bcnt, tmp, E, NBKT,
        x, wt1, a1s, a1d, h1, alsrc1, aldst1, N, nbBin);

    // 3. bucket CSR
    bucket_csr_kernel<<<NBKT, 256, 0, stream>>>(tmp, bcnt, deg, offsets,
                                                src_sorted, N);

    // 4. agg layer-1 + layer-2 MFMA transform (fused, no fb16 roundtrip)
    aggtrans_mfma_kernel<<<nbT, 256, 0, stream>>>(
        offsets, deg, src_sorted, h1, alsrc1, aldst1, b1,
        wt2, a2s, a2d, h2, alsrc2, aldst2, N);

    // 5. agg layer-2 + layer-3 VALU transform (fused)
    aggtrans_valu_kernel<<<nbT, 256, 0, stream>>>(
        offsets, deg, src_sorted, h2, alsrc2, aldst2, b2,
        W3, a3s, a3d, h3, alsrc3, aldst3, N);

    // 6. agg layer-3 + classification head
    gat_agg3_kernel<<<nbT, 256, 0, stream>>>(
        offsets, deg, src_sorted, h3, alsrc3, aldst3, b3, link_out,
        Wc, bc, node_out, N);
}

// Round 4
// 271.094 us; speedup vs baseline: 1.5816x; 1.5816x over previous
//
#include <hip/hip_runtime.h>
#include <math.h>

#define SLOPE 0.2f

__device__ __forceinline__ float lrelu(float x) { return x > 0.f ? x : SLOPE * x; }

// bf16 helpers
__device__ __forceinline__ float bflo(unsigned int u) { return __uint_as_float(u << 16); }
__device__ __forceinline__ float bfhi(unsigned int u) { return __uint_as_float(u & 0xffff0000u); }
__device__ __forceinline__ unsigned short f2bf(float f) {   // round-nearest-even
    unsigned int u = __float_as_uint(f);
    unsigned int r = u + 0x7fffu + ((u >> 16) & 1u);
    return (unsigned short)(r >> 16);
}

typedef short frag8 __attribute__((ext_vector_type(8)));   // 8 bf16 (4 VGPR)
typedef float f32x4 __attribute__((ext_vector_type(4)));   // MFMA acc

// ---------------------------------------------------------------------------
// One-off: Wt[n][k] = bf16(W[k][n]) for W1 and W2 (128x128 each).
// Also zeroes bcnt (replaces a hipMemsetAsync dispatch).
// ---------------------------------------------------------------------------
__global__ __launch_bounds__(256) void wtrans_kernel(
    const float* __restrict__ W1, const float* __restrict__ W2,
    unsigned short* __restrict__ Wt1, unsigned short* __restrict__ Wt2,
    int* __restrict__ bcnt, int nbcnt)
{
    int idx = blockIdx.x * 256 + threadIdx.x;   // grid 128 -> 32768
    if (idx < nbcnt) bcnt[idx] = 0;
    const float* W = W1;
    unsigned short* Wt = Wt1;
    int i = idx;
    if (idx >= 16384) { W = W2; Wt = Wt2; i = idx - 16384; }
    int n = i >> 7, k = i & 127;
    Wt[i] = f2bf(W[k * 128 + n]);
}

// ---------------------------------------------------------------------------
// MFMA transform body for layers 1-2 (CIN=128 -> COUT=128, H=4), input fp32
// or bf16 (templated). h = bf16(x) @ bf16(W), fp32 acc, mfma_f32_16x16x32_bf16.
// Block: 64 nodes x 128 cols, 4 waves; wave w = head w, 8 acc tiles.
// ---------------------------------------------------------------------------
#define TF_MB 64
#define TF_LDK 136

template <bool BF16IN>
__device__ __forceinline__ void transform_body(
    int bid, const void* __restrict__ xin, const unsigned short* __restrict__ Wt,
    const float* __restrict__ a_src, const float* __restrict__ a_dst,
    unsigned short* __restrict__ hout, float* __restrict__ alsrc,
    float* __restrict__ aldst, int N,
    unsigned short* xs, unsigned short* wt)
{
    constexpr int MB = TF_MB;
    constexpr int LDK = TF_LDK;

    const int node0 = bid * MB;
    const int t = threadIdx.x;

    if constexpr (BF16IN) {
        const unsigned short* xb = (const unsigned short*)xin;
        for (int i = t; i < MB * 16; i += 256) {         // 16 uint4 per row
            int row = i >> 4, c16 = i & 15;
            uint4 v = make_uint4(0u, 0u, 0u, 0u);
            if (node0 + row < N)
                v = ((const uint4*)(xb + (size_t)(node0 + row) * 128))[c16];
            *(uint4*)&xs[row * LDK + c16 * 8] = v;
        }
    } else {
        const float* xf = (const float*)xin;
        for (int i = t; i < MB * 32; i += 256) {
            int row = i >> 5, col4 = i & 31;
            ushort4 o;
            if (node0 + row < N) {
                float4 v = ((const float4*)(xf + (size_t)(node0 + row) * 128))[col4];
                o.x = f2bf(v.x); o.y = f2bf(v.y); o.z = f2bf(v.z); o.w = f2bf(v.w);
            } else {
                o.x = o.y = o.z = o.w = 0;
            }
            *(ushort4*)&xs[row * LDK + col4 * 4] = o;
        }
    }
    for (int i = t; i < 2048; i += 256) {                // Wt: 2048 x 16B
        int n = i >> 4, k16 = i & 15;
        uint4 v = ((const uint4*)Wt)[i];
        *(uint4*)&wt[n * LDK + k16 * 8] = v;
    }
    __syncthreads();

    const int w    = t >> 6;             // wave = head
    const int lane = t & 63;
    const int r    = lane & 15;
    const int q    = lane >> 4;

    f32x4 acc[4][2];
#pragma unroll
    for (int mt = 0; mt < 4; ++mt)
#pragma unroll
        for (int nl = 0; nl < 2; ++nl)
            acc[mt][nl] = (f32x4){0.f, 0.f, 0.f, 0.f};

#pragma unroll
    for (int kk = 0; kk < 4; ++kk) {
        const int kof = kk * 32 + q * 8;
        frag8 b0 = *(const frag8*)&wt[(w * 32 + r) * LDK + kof];
        frag8 b1 = *(const frag8*)&wt[(w * 32 + 16 + r) * LDK + kof];
#pragma unroll
        for (int mt = 0; mt < 4; ++mt) {
            frag8 a = *(const frag8*)&xs[(mt * 16 + r) * LDK + kof];
            acc[mt][0] = __builtin_amdgcn_mfma_f32_16x16x32_bf16(a, b0, acc[mt][0], 0, 0, 0);
            acc[mt][1] = __builtin_amdgcn_mfma_f32_16x16x32_bf16(a, b1, acc[mt][1], 0, 0, 0);
        }
    }

    // ---- logits from fp32 acc ----
    const float as0 = a_src[w * 32 + r],      ad0 = a_dst[w * 32 + r];
    const float as1 = a_src[w * 32 + 16 + r], ad1 = a_dst[w * 32 + 16 + r];
#pragma unroll
    for (int mt = 0; mt < 4; ++mt) {
#pragma unroll
        for (int reg = 0; reg < 4; ++reg) {
            float s = acc[mt][0][reg] * as0 + acc[mt][1][reg] * as1;
            float d = acc[mt][0][reg] * ad0 + acc[mt][1][reg] * ad1;
#pragma unroll
            for (int off = 1; off < 16; off <<= 1) {
                s += __shfl_xor(s, off);
                d += __shfl_xor(d, off);
            }
            if (r == 0) {
                int m = mt * 16 + q * 4 + reg;
                int n = node0 + m;
                if (n < N) {
                    alsrc[n * 4 + w] = s;
                    aldst[n * 4 + w] = d;
                }
            }
        }
    }

    // ---- h -> LDS (bf16, D-layout scatter), then coalesced global store ----
    __syncthreads();
#pragma unroll
    for (int mt = 0; mt < 4; ++mt)
#pragma unroll
        for (int nl = 0; nl < 2; ++nl)
#pragma unroll
            for (int reg = 0; reg < 4; ++reg) {
                int m = mt * 16 + q * 4 + reg;
                int n = w * 32 + nl * 16 + r;
                xs[m * LDK + n] = f2bf(acc[mt][nl][reg]);
            }
    __syncthreads();
    {
        int row = t >> 2, cbase = (t & 3) * 32;      // 4 threads/row, 32 bf16 each
        if (node0 + row < N) {
            uint4* dst = (uint4*)(hout + (size_t)(node0 + row) * 128 + cbase);
#pragma unroll
            for (int j = 0; j < 4; ++j)
                dst[j] = *(const uint4*)&xs[row * LDK + cbase + j * 8];
        }
    }
}

template <bool BF16IN>
__global__ __launch_bounds__(256) void transform_mfma_kernel(
    const void* __restrict__ xin, const unsigned short* __restrict__ Wt,
    const float* __restrict__ a_src, const float* __restrict__ a_dst,
    unsigned short* __restrict__ hout, float* __restrict__ alsrc,
    float* __restrict__ aldst, int N)
{
    __shared__ __align__(16) unsigned short xs[TF_MB * TF_LDK];
    __shared__ __align__(16) unsigned short wt[128 * TF_LDK];
    transform_body<BF16IN>(blockIdx.x, xin, Wt, a_src, a_dst, hout,
                           alsrc, aldst, N, xs, wt);
}

// ---------------------------------------------------------------------------
// VALU transform for layer 3 (CIN=128 bf16 -> COUT=32, H=1), fused logits.
// ---------------------------------------------------------------------------
template <int COUT, int Hh, int NPT>
__global__ __launch_bounds__(256) void transform_kernel(
    const unsigned short* __restrict__ xin, const float* __restrict__ W,
    const float* __restrict__ a_src, const float* __restrict__ a_dst,
    unsigned short* __restrict__ hout, float* __restrict__ alsrc,
    float* __restrict__ aldst, int N)
{
    constexpr int JT = COUT / 4;
    constexpr int GROUPS = 256 / JT;
    constexpr int NB = GROUPS * NPT;
    constexpr int PAD = 4;
    __shared__ __align__(16) float xs[NB][128 + PAD];

    const int node0 = blockIdx.x * NB;
    for (int i = threadIdx.x; i < NB * 16; i += 256) {   // 16 uint4/row (bf16)
        int row = i >> 4, c16 = i & 15;
        uint4 v = make_uint4(0u, 0u, 0u, 0u);
        if (node0 + row < N)
            v = ((const uint4*)(xin + (size_t)(node0 + row) * 128))[c16];
        float* xp = &xs[row][c16 * 8];
        xp[0] = bflo(v.x); xp[1] = bfhi(v.x);
        xp[2] = bflo(v.y); xp[3] = bfhi(v.y);
        xp[4] = bflo(v.z); xp[5] = bfhi(v.z);
        xp[6] = bflo(v.w); xp[7] = bfhi(v.w);
    }
    __syncthreads();

    const int jt = threadIdx.x % JT;
    const int g  = threadIdx.x / JT;
    const int j4 = jt * 4;

    float4 acc[NPT];
#pragma unroll
    for (int m = 0; m < NPT; ++m) acc[m] = make_float4(0.f, 0.f, 0.f, 0.f);

    const float4* Wf4 = (const float4*)W;
    for (int k4 = 0; k4 < 32; ++k4) {
        float4 w0 = Wf4[(4 * k4 + 0) * JT + jt];
        float4 w1 = Wf4[(4 * k4 + 1) * JT + jt];
        float4 w2 = Wf4[(4 * k4 + 2) * JT + jt];
        float4 w3 = Wf4[(4 * k4 + 3) * JT + jt];
#pragma unroll
        for (int m = 0; m < NPT; ++m) {
            float4 xv = *(const float4*)&xs[g * NPT + m][k4 << 2];
            acc[m].x += xv.x * w0.x + xv.y * w1.x + xv.z * w2.x + xv.w * w3.x;
            acc[m].y += xv.x * w0.y + xv.y * w1.y + xv.z * w2.y + xv.w * w3.y;
            acc[m].z += xv.x * w0.z + xv.y * w1.z + xv.z * w2.z + xv.w * w3.z;
            acc[m].w += xv.x * w0.w + xv.y * w1.w + xv.z * w2.w + xv.w * w3.w;
        }
    }

    const float4 as4 = ((const float4*)a_src)[jt];
    const float4 ad4 = ((const float4*)a_dst)[jt];
    const int hh = j4 >> 5;

#pragma unroll
    for (int m = 0; m < NPT; ++m) {
        int n = node0 + g * NPT + m;
        float4 v = acc[m];
        float sv = v.x * as4.x + v.y * as4.y + v.z * as4.z + v.w * as4.w;
        float dv = v.x * ad4.x + v.y * ad4.y + v.z * ad4.z + v.w * ad4.w;
#pragma unroll
        for (int off = 4; off >= 1; off >>= 1) {
            sv += __shfl_xor(sv, off);
            dv += __shfl_xor(dv, off);
        }
        if (n < N) {
            ushort4 hp;
            hp.x = f2bf(v.x); hp.y = f2bf(v.y);
            hp.z = f2bf(v.z); hp.w = f2bf(v.w);
            ((ushort4*)(hout + (size_t)n * COUT))[jt] = hp;
            if ((jt & 7) == 0) {
                alsrc[n * Hh + hh] = sv;
                aldst[n * Hh + hh] = dv;
            }
        }
    }
}

// ---------------------------------------------------------------------------
// CSR build, bucket-local counting sort (64 dst nodes per bucket).
// ---------------------------------------------------------------------------
#define BKT_CAP 2048
#define NBKT_MAX 1024
#define CH_BIN 4096

__device__ __forceinline__ void bin_body(
    int bid, const int* __restrict__ src, const int* __restrict__ dst,
    int* __restrict__ bcnt, unsigned int* __restrict__ tmp, int E, int nbkt,
    int* hist, int* base)
{
    const int e0 = bid * CH_BIN;
    const int e1 = min(e0 + CH_BIN, E);

    for (int b = threadIdx.x; b < nbkt; b += 256) hist[b] = 0;
    __syncthreads();
    for (int e = e0 + threadIdx.x; e < e1; e += 256) {
        int d = __builtin_nontemporal_load(dst + e);
        atomicAdd(&hist[d >> 6], 1);
    }
    __syncthreads();
    for (int b = threadIdx.x; b < nbkt; b += 256) {
        int c = hist[b];
        base[b] = (c > 0) ? atomicAdd(&bcnt[b << 4], c) : 0;  // 64B-strided
        hist[b] = 0;
    }
    __syncthreads();
    for (int e = e0 + threadIdx.x; e < e1; e += 256) {
        int d = __builtin_nontemporal_load(dst + e);
        int s = __builtin_nontemporal_load(src + e);
        int b = d >> 6;
        int pos = base[b] + atomicAdd(&hist[b], 1);
        if (pos < BKT_CAP)
            tmp[((size_t)b << 11) + pos] =
                ((unsigned int)s << 6) | (unsigned int)(d & 63);
    }
}

// Fused: blocks [0, nbin) bin edges, blocks [nbin, ...) run the layer-1 MFMA
// transform (independent work, shared dispatch).
__global__ __launch_bounds__(256) void bin_transform_kernel(
    const int* __restrict__ src, const int* __restrict__ dst,
    int* __restrict__ bcnt, unsigned int* __restrict__ tmp, int E, int nbkt,
    const float* __restrict__ xin, const unsigned short* __restrict__ Wt,
    const float* __restrict__ a_src, const float* __restrict__ a_dst,
    unsigned short* __restrict__ hout, float* __restrict__ alsrc,
    float* __restrict__ aldst, int N, int nbin)
{
    __shared__ __align__(16) unsigned short smem[TF_MB * TF_LDK + 128 * TF_LDK];
    if ((int)blockIdx.x < nbin) {
        int* hist = (int*)smem;
        bin_body(blockIdx.x, src, dst, bcnt, tmp, E, nbkt, hist, hist + NBKT_MAX);
    } else {
        transform_body<false>(blockIdx.x - nbin, xin, Wt, a_src, a_dst,
                              hout, alsrc, aldst, N, smem, smem + TF_MB * TF_LDK);
    }
}

__global__ __launch_bounds__(256) void bucket_csr_kernel(
    const unsigned int* __restrict__ tmp, const int* __restrict__ bcnt,
    int* __restrict__ deg, int* __restrict__ offsets,
    int* __restrict__ src_sorted, int N)
{
    int b = blockIdx.x;
    __shared__ int hist[64];
    if (threadIdx.x < 64) hist[threadIdx.x] = 0;
    __syncthreads();
    int cnt = min(bcnt[b << 4], BKT_CAP);
    const unsigned int* tb = tmp + ((size_t)b << 11);
    for (int i = threadIdx.x; i < cnt; i += 256)
        atomicAdd(&hist[tb[i] & 63u], 1);
    __syncthreads();
    if (threadIdx.x < 64) {                          // wave 0: 64-wide scan
        int v = hist[threadIdx.x];
        int incl = v;
#pragma unroll
        for (int off = 1; off < 64; off <<= 1) {
            int t2 = __shfl_up(incl, off);
            if ((int)threadIdx.x >= off) incl += t2;
        }
        int excl = incl - v;
        int node = (b << 6) + threadIdx.x;
        if (node < N) {
            deg[node] = v;
            offsets[node] = (b << 11) + excl;
        }
        hist[threadIdx.x] = excl;                    // reuse as cursor
    }
    __syncthreads();
    for (int i = threadIdx.x; i < cnt; i += 256) {
        unsigned int p = tb[i];
        int pos = atomicAdd(&hist[p & 63u], 1);
        src_sorted[((size_t)b << 11) + pos] = (int)(p >> 6);
    }
}

// ---------------------------------------------------------------------------
// BARRIER-FREE GAT aggregation (per-node gather, zero atomics, zero LDS),
// bf16 h. Each TPN-thread group streams its node's edge list independently:
// per edge, each thread loads the src index + its OWN head's src logit
// (same-address across the head's lanes -> HW broadcast) and computes the
// softmax weight redundantly (1 exp/edge/thread, hidden under the gather).
// No __syncthreads anywhere -> waves never stall on block-mates; x4 unroll
// keeps 4 independent 256B row gathers in flight. __launch_bounds__(256,8)
// pins VGPR<=64 so the full 32 waves/CU stay resident (R3 showed agg
// throughput ~ occupancy).
// OUTBF: write bf16 activations (layers 1-2). FUSE_HEAD: layer-3 head fused.
// ---------------------------------------------------------------------------
__device__ __forceinline__ void fma8(const uint4& p, float w, float* a) {
    a[0] += w * bflo(p.x); a[1] += w * bfhi(p.x);
    a[2] += w * bflo(p.y); a[3] += w * bfhi(p.y);
    a[4] += w * bflo(p.z); a[5] += w * bfhi(p.z);
    a[6] += w * bflo(p.w); a[7] += w * bfhi(p.w);
}

template <int Hh, int Cc, bool DO_ELU, bool OUTBF, bool FUSE_HEAD>
__global__ __launch_bounds__(256, 8) void gat_agg_kernel(
    const int* __restrict__ offsets, const int* __restrict__ deg_arr,
    const int* __restrict__ src_sorted,
    const unsigned short* __restrict__ h, const float* __restrict__ alsrc,
    const float* __restrict__ aldst, const float* __restrict__ bias,
    void* __restrict__ outv, const float* __restrict__ Wc,
    const float* __restrict__ bc, float* __restrict__ node_out, int N)
{
    constexpr int HC  = Hh * Cc;
    constexpr int TPN = HC / 8;          // threads per node (16 or 4)
    constexpr int NPB = 256 / TPN;       // nodes per block

    const int g  = threadIdx.x / TPN;
    const int lt = threadIdx.x % TPN;
    const int n  = blockIdx.x * NPB + g;
    if (n >= N) return;                  // no barriers below -> safe

    const int off0 = offsets[n];
    const int deg  = deg_arr[n];
    const int hh   = (lt * 8) / Cc;      // this thread's head
    const float adv = aldst[(size_t)n * Hh + hh];
    const uint4* h4 = (const uint4*)h;
    const int* el = src_sorted + off0;

    float a[8] = {0.f, 0.f, 0.f, 0.f, 0.f, 0.f, 0.f, 0.f};

    // self-loop first (frees its registers before the main loop)
    float den;
    {
        float wself = __expf(lrelu(alsrc[(size_t)n * Hh + hh] + adv));
        fma8(h4[(size_t)n * TPN + lt], wself, a);
        den = wself + 1e-16f;
    }

    int e = 0;
    for (; e + 3 < deg; e += 4) {
        int s0 = el[e], s1 = el[e + 1], s2 = el[e + 2], s3 = el[e + 3];
        float l0 = alsrc[(size_t)s0 * Hh + hh];
        float l1 = alsrc[(size_t)s1 * Hh + hh];
        float l2 = alsrc[(size_t)s2 * Hh + hh];
        float l3 = alsrc[(size_t)s3 * Hh + hh];
        uint4 p0 = h4[(size_t)s0 * TPN + lt];
        uint4 p1 = h4[(size_t)s1 * TPN + lt];
        uint4 p2 = h4[(size_t)s2 * TPN + lt];
        uint4 p3 = h4[(size_t)s3 * TPN + lt];
        float w0 = __expf(lrelu(l0 + adv));
        float w1 = __expf(lrelu(l1 + adv));
        float w2 = __expf(lrelu(l2 + adv));
        float w3 = __expf(lrelu(l3 + adv));
        fma8(p0, w0, a);
        fma8(p1, w1, a);
        fma8(p2, w2, a);
        fma8(p3, w3, a);
        den += (w0 + w1) + (w2 + w3);
    }
    for (; e < deg; ++e) {
        int s0 = el[e];
        float l0 = alsrc[(size_t)s0 * Hh + hh];
        uint4 p0 = h4[(size_t)s0 * TPN + lt];
        float w0 = __expf(lrelu(l0 + adv));
        fma8(p0, w0, a);
        den += w0;
    }

    {
        float inv = 1.f / den;
        float4 bv0 = ((const float4*)bias)[lt * 2];
        float4 bv1 = ((const float4*)bias)[lt * 2 + 1];
        float o[8];
        o[0] = a[0] * inv + bv0.x; o[1] = a[1] * inv + bv0.y;
        o[2] = a[2] * inv + bv0.z; o[3] = a[3] * inv + bv0.w;
        o[4] = a[4] * inv + bv1.x; o[5] = a[5] * inv + bv1.y;
        o[6] = a[6] * inv + bv1.z; o[7] = a[7] * inv + bv1.w;
        if (DO_ELU) {
#pragma unroll
            for (int q = 0; q < 8; ++q)
                o[q] = o[q] > 0.f ? o[q] : __expf(o[q]) - 1.f;
        }
        if constexpr (OUTBF) {
            unsigned short* ob = (unsigned short*)outv;
            uint4 pk;
            pk.x = (unsigned int)f2bf(o[0]) | ((unsigned int)f2bf(o[1]) << 16);
            pk.y = (unsigned int)f2bf(o[2]) | ((unsigned int)f2bf(o[3]) << 16);
            pk.z = (unsigned int)f2bf(o[4]) | ((unsigned int)f2bf(o[5]) << 16);
            pk.w = (unsigned int)f2bf(o[6]) | ((unsigned int)f2bf(o[7]) << 16);
            ((uint4*)(ob + (size_t)n * HC))[lt] = pk;
        } else {
            float* of = (float*)outv;
            float4* op = (float4*)(of + (size_t)n * HC);
            op[lt * 2]     = make_float4(o[0], o[1], o[2], o[3]);
            op[lt * 2 + 1] = make_float4(o[4], o[5], o[6], o[7]);
        }
        if constexpr (FUSE_HEAD) {
            // node_out[n,k] = sum_c o_full[c]*Wc[c,k] + bc[k], k in {0,1}
            float s0 = 0.f, s1 = 0.f;
#pragma unroll
            for (int q = 0; q < 8; ++q) {
                int c = lt * 8 + q;
                s0 += o[q] * Wc[c * 2];
                s1 += o[q] * Wc[c * 2 + 1];
            }
            s0 += __shfl_xor(s0, 1); s0 += __shfl_xor(s0, 2);
            s1 += __shfl_xor(s1, 1); s1 += __shfl_xor(s1, 2);
            if (lt == 0) {
                node_out[(size_t)n * 2]     = s0 + bc[0];
                node_out[(size_t)n * 2 + 1] = s1 + bc[1];
            }
        }
    }
}

extern "C" void kernel_launch(void* const* d_in, const int* in_sizes, int n_in,
                              void* d_out, int out_size, void* d_ws, size_t ws_size,
                              hipStream_t stream)
{
    const float* x   = (const float*)d_in[0];
    const int*   ei  = (const int*)d_in[1];
    const float* W1  = (const float*)d_in[2];
    const float* a1s = (const float*)d_in[3];
    const float* a1d = (const float*)d_in[4];
    const float* b1  = (const float*)d_in[5];
    const float* W2  = (const float*)d_in[6];
    const float* a2s = (const float*)d_in[7];
    const float* a2d = (const float*)d_in[8];
    const float* b2  = (const float*)d_in[9];
    const float* W3  = (const float*)d_in[10];
    const float* a3s = (const float*)d_in[11];
    const float* a3d = (const float*)d_in[12];
    const float* b3  = (const float*)d_in[13];
    const float* Wc  = (const float*)d_in[14];
    const float* bc  = (const float*)d_in[15];

    const int N = in_sizes[0] / 128;
    const int E = in_sizes[1] / 2;
    const int* srcIdx = ei;
    const int* dstIdx = ei + E;

    const int NBKT = (N + 63) >> 6;

    // ws layout (16B-aligned where vector loads require it)
    float* alsrc = (float*)d_ws;                        // N*4
    float* aldst = alsrc + (size_t)N * 4;               // N*4
    unsigned short* fb16 = (unsigned short*)(aldst + (size_t)N * 4); // N*128 bf16
    unsigned short* hbuf = fb16 + (size_t)N * 128;      // N*128 bf16
    int* deg        = (int*)(hbuf + (size_t)N * 128);   // N
    int* offsets    = deg + N;                          // N
    uintptr_t wp = ((uintptr_t)(offsets + N) + 15) & ~(uintptr_t)15;
    unsigned short* wt1 = (unsigned short*)wp;          // 16384 bf16, 16B-aligned
    unsigned short* wt2 = wt1 + 16384;                  // 16384 bf16
    int* bcnt       = (int*)(wt2 + 16384);              // NBKT*16 (64B-strided)
    int* src_sorted = bcnt + (size_t)NBKT * 16;         // NBKT*BKT_CAP
    unsigned int* tmp = (unsigned int*)(src_sorted + (size_t)NBKT * BKT_CAP);

    float* node_out = (float*)d_out;                    // N*2
    float* link_out = node_out + (size_t)N * 2;         // N*32

    const int nbBin = (E + CH_BIN - 1) / CH_BIN;
    const int nbT   = (N + 63) / 64;

    // ---------------- W pre-transpose (bf16) + bcnt zero --------------------
    wtrans_kernel<<<128, 256, 0, stream>>>(W1, W2, wt1, wt2, bcnt, NBKT * 16);

    // -------- edge binning  ∥  layer-1 transform (independent, fused) -------
    bin_transform_kernel<<<nbBin + nbT, 256, 0, stream>>>(
        srcIdx, dstIdx, bcnt, tmp, E, NBKT,
        x, wt1, a1s, a1d, hbuf, alsrc, aldst, N, nbBin);

    // ---------------- bucket CSR (short) ------------------------------------
    bucket_csr_kernel<<<NBKT, 256, 0, stream>>>(tmp, bcnt, deg, offsets,
                                                src_sorted, N);

    // ---------------- layer 1 aggregation (ELU) -----------------------------
    gat_agg_kernel<4, 32, true, true, false><<<(N + 15) / 16, 256, 0, stream>>>(
        offsets, deg, src_sorted, hbuf, alsrc, aldst, b1, fb16,
        nullptr, nullptr, nullptr, N);

    // ---------------- layer 2 (128 bf16 -> H=4,C=32, concat, ELU) -----------
    transform_mfma_kernel<true><<<nbT, 256, 0, stream>>>(
        fb16, wt2, a2s, a2d, hbuf, alsrc, aldst, N);
    gat_agg_kernel<4, 32, true, true, false><<<(N + 15) / 16, 256, 0, stream>>>(
        offsets, deg, src_sorted, hbuf, alsrc, aldst, b2, fb16,
        nullptr, nullptr, nullptr, N);

    // ---------------- layer 3 (128 bf16 -> H=1,C=32) + fused head -----------
    transform_kernel<32, 1, 4><<<(N + 127) / 128, 256, 0, stream>>>(
        fb16, W3, a3s, a3d, hbuf, alsrc, aldst, N);
    gat_agg_kernel<1, 32, false, false, true><<<(N + 63) / 64, 256, 0, stream>>>(
        offsets, deg, src_sorted, hbuf, alsrc, aldst, b3, link_out,
        Wc, bc, node_out, N);
}